// Round 1
// baseline (391.846 us; speedup 1.0000x reference)
//
#include <hip/hip_runtime.h>

#define T_PATCH 256
#define C_DIM   768
#define NCH     48      // C_DIM / 16
#define N_B     8
#define N_N     32

typedef unsigned short u16;
typedef u16   u16x8  __attribute__((ext_vector_type(8)));
typedef short s16x8  __attribute__((ext_vector_type(8)));
typedef float f32x16 __attribute__((ext_vector_type(16)));

__device__ __forceinline__ unsigned rne16(unsigned u) {
    // fp32 bits -> bf16 bits, round-to-nearest-even
    return (u + 0x7fffu + ((u >> 16) & 1u)) >> 16;
}

// 3-way RNE bf16 split: x ~= h0 + h1 + h2, |h1|<=2^-8|x|, |h2|<=2^-16|x|
__device__ __forceinline__ void split3(float x, u16& o0, u16& o1, u16& o2) {
    unsigned u0 = rne16(__float_as_uint(x));
    float f0 = __uint_as_float(u0 << 16);
    float r1 = x - f0;
    unsigned u1 = rne16(__float_as_uint(r1));
    float f1 = __uint_as_float(u1 << 16);
    float r2 = r1 - f1;
    o0 = (u16)u0; o1 = (u16)u1; o2 = (u16)(__float_as_uint(r2) >> 16);
}

// ---------------- kernel 0a: pre-split tar into 3 bf16 planes (MFMA-fragment layout) ----
// plane layout: [b][chunk][g][t][8]  (slot index = (b*48+c)*512 + g*256 + t)
// NOTE: this layout IS the A-fragment layout; sim_kernel now reads fragments
// directly from these planes (L2-resident) instead of staging A in LDS.
__global__ void tar_split_kernel(const float* __restrict__ tar,
                                 u16* __restrict__ tS0, u16* __restrict__ tS1,
                                 u16* __restrict__ tS2, float* __restrict__ partT) {
    int blk = blockIdx.x;            // b*48 + c
    int b = blk / NCH, c = blk - b * NCH;
    int tid = threadIdx.x;           // 0..511
    int g = tid >> 8, t = tid & 255;
    const float* tb = tar + (size_t)b * C_DIM * T_PATCH;
    float ss = 0.f;
    u16x8 v0, v1, v2;
    #pragma unroll
    for (int j = 0; j < 8; ++j) {
        float x = tb[(c * 16 + g * 8 + j) * T_PATCH + t];
        u16 a, bb, cc;
        split3(x, a, bb, cc);
        v0[j] = a; v1[j] = bb; v2[j] = cc;
        ss = fmaf(x, x, ss);
    }
    size_t off = ((size_t)blk * 512 + tid) * 8;
    *(u16x8*)(tS0 + off) = v0;
    *(u16x8*)(tS1 + off) = v1;
    *(u16x8*)(tS2 + off) = v2;
    __shared__ float sq[512];
    sq[tid] = ss;
    __syncthreads();
    if (tid < 256) partT[blk * 256 + tid] = sq[tid] + sq[tid + 256];
}

// ---------------- kernel 0b: tar inverse norms (tm folded) ----------------
__global__ void invt_kernel(const float* __restrict__ partT,
                            const float* __restrict__ tar_mask,
                            float* __restrict__ w_invT) {
    int b = blockIdx.x, t = threadIdx.x;
    float s = 0.f;
    for (int c = 0; c < NCH; ++c) s += partT[(b * NCH + c) * 256 + t];
    float tm = tar_mask[b * 256 + t];
    w_invT[b * 256 + t] = (tm != 0.f) ? 1.f / fmaxf(sqrtf(s), 1e-12f) : 0.f;
}

// ---------------- kernel 1: per-(b,n,half) GEMM + partial argmax ----------------
// Round-6 restructure: single-barrier double-buffered pipeline.
//  - A fragments read DIRECTLY from the pre-split global planes (L2 hits;
//    layout already matches the fragment). No A LDS, no A ds_write.
//  - B tile double-buffered in LDS (12 KB x 2); exactly ONE __syncthreads per
//    k-chunk (write buf[p^1] / read buf[p]; WAR+RAW both covered).
//  - T14 async-stage split: next chunk's yv global loads issued BEFORE the
//    MFMA cluster, split3 + ds_write AFTER it -> HBM latency hides under MFMA.
//  - T5 setprio(1) around the MFMA cluster (schedule now has role-split).
//  - XCD swizzle: b = blockIdx&7 so each XCD's L2 keeps one b's tar planes.
// Round-2 lesson: launch_bounds(512,4) caps 128 regs total; spill => WRITE_SIZE blows up.
__launch_bounds__(512, 4)
__global__ void sim_kernel(const float* __restrict__ src_feats,
                           const u16* __restrict__ tS0, const u16* __restrict__ tS1,
                           const u16* __restrict__ tS2,
                           const float* __restrict__ w_invT,
                           const float* __restrict__ src_masks,
                           float* __restrict__ w_rowv, int* __restrict__ w_rowi,
                           float* __restrict__ w_s2tv, int* __restrict__ w_s2ti) {
    __shared__ __align__(16) u16 B0[2][2][128][8], B1[2][2][128][8], B2[2][2][128][8]; // 24 KB
    __shared__ float sqS[2][128];
    __shared__ float rowv[2][256]; __shared__ int rowi[2][256];
    __shared__ float colv[4][128]; __shared__ int coli[4][128];
    __shared__ float invT[256], invS[128];

    int bh = blockIdx.x;
    // XCD swizzle: consecutive blockIdx round-robin across the 8 XCDs.
    int b    = bh & 7;          // XCD id == batch -> per-XCD L2 holds this b's planes
    int loc  = bh >> 3;         // 0..63
    int n    = loc >> 1;
    int half = loc & 1;
    int bn   = b * N_N + n;
    int lbh  = bn * 2 + half;   // logical (b,n,half) index for outputs

    int tid = threadIdx.x;
    int lane = tid & 63, w = tid >> 6;     // 8 waves
    int wm = w >> 1, wn = w & 1;           // 4 m-groups x 2 n-groups (64x64 tile)
    int h = lane >> 5, l5 = lane & 31;
    int colB = tid & 127, gB = (tid >> 7) & 1;   // B staging slot (tid<256)

    // B source: column colB, k-half gB of each chunk
    const float* sB = src_feats + (size_t)bn * C_DIM * T_PATCH
                    + (size_t)gB * 8 * T_PATCH + half * 128 + colB;
    // A fragment pointers (advance 4096 u16 per chunk); frag row for lane
    size_t aoff = ((size_t)b * NCH) * 4096 + (size_t)(h * 256 + wm * 64 + l5) * 8;
    const u16* pa0 = tS0 + aoff;
    const u16* pa1 = tS1 + aoff;
    const u16* pa2 = tS2 + aoff;

    if (tid < 256) invT[tid] = w_invT[b * 256 + tid];

    f32x16 acc[2][2];
    #pragma unroll
    for (int i = 0; i < 2; ++i)
        #pragma unroll
        for (int j = 0; j < 2; ++j) acc[i][j] = (f32x16)0.0f;

    float sss = 0.f;

    // ---- prologue: stage chunk 0 into buffer 0
    if (tid < 256) {
        u16x8 b0v, b1v, b2v;
        #pragma unroll
        for (int j = 0; j < 8; ++j) {
            float x = sB[j * T_PATCH];
            u16 a, bb, cc;
            split3(x, a, bb, cc);
            b0v[j] = a; b1v[j] = bb; b2v[j] = cc;
            sss = fmaf(x, x, sss);
        }
        ((u16x8*)B0[0])[tid] = b0v;   // slot = gB*128 + colB = tid
        ((u16x8*)B1[0])[tid] = b1v;
        ((u16x8*)B2[0])[tid] = b2v;
    }
    const float* psrc = sB + 4096;    // next-chunk prefetch base
    __syncthreads();

    for (int c = 0; c < NCH; ++c) {
        int p = c & 1;
        // A fragments for THIS chunk: direct global loads (L2-resident planes,
        // fragment-order layout). Issued first so vmcnt waits leave yv in flight.
        s16x8 a0[2], a1[2], a2[2];
        #pragma unroll
        for (int i = 0; i < 2; ++i) {
            a0[i] = *(const s16x8*)(pa0 + i * 256);
            a1[i] = *(const s16x8*)(pa1 + i * 256);
            a2[i] = *(const s16x8*)(pa2 + i * 256);
        }
        pa0 += 4096; pa1 += 4096; pa2 += 4096;

        // T14 issue-early: next chunk's B source loads; consumed after MFMA.
        float yv[8];
        bool pf = (c < NCH - 1);
        if (tid < 256 && pf) {
            #pragma unroll
            for (int j = 0; j < 8; ++j) yv[j] = psrc[j * T_PATCH];
            psrc += 4096;
        }

        // ---- MFMA cluster on buffer p
        __builtin_amdgcn_s_setprio(1);
        #pragma unroll
        for (int j = 0; j < 2; ++j) {
            int cl = wn * 64 + j * 32 + l5;
            s16x8 b0 = *(const s16x8*)&B0[p][h][cl][0];
            s16x8 b1 = *(const s16x8*)&B1[p][h][cl][0];
            s16x8 b2 = *(const s16x8*)&B2[p][h][cl][0];
            #pragma unroll
            for (int i = 0; i < 2; ++i) {
                acc[i][j] = __builtin_amdgcn_mfma_f32_32x32x16_bf16(a0[i], b0, acc[i][j], 0, 0, 0);
                acc[i][j] = __builtin_amdgcn_mfma_f32_32x32x16_bf16(a0[i], b1, acc[i][j], 0, 0, 0);
                acc[i][j] = __builtin_amdgcn_mfma_f32_32x32x16_bf16(a1[i], b0, acc[i][j], 0, 0, 0);
                acc[i][j] = __builtin_amdgcn_mfma_f32_32x32x16_bf16(a1[i], b1, acc[i][j], 0, 0, 0);
                acc[i][j] = __builtin_amdgcn_mfma_f32_32x32x16_bf16(a0[i], b2, acc[i][j], 0, 0, 0);
                acc[i][j] = __builtin_amdgcn_mfma_f32_32x32x16_bf16(a2[i], b0, acc[i][j], 0, 0, 0);
            }
        }
        __builtin_amdgcn_s_setprio(0);

        // ---- write-late: split3 + stage into buffer p^1
        if (tid < 256 && pf) {
            u16x8 b0v, b1v, b2v;
            #pragma unroll
            for (int j = 0; j < 8; ++j) {
                u16 a, bb, cc;
                split3(yv[j], a, bb, cc);
                b0v[j] = a; b1v[j] = bb; b2v[j] = cc;
                sss = fmaf(yv[j], yv[j], sss);
            }
            ((u16x8*)B0[p ^ 1])[tid] = b0v;
            ((u16x8*)B1[p ^ 1])[tid] = b1v;
            ((u16x8*)B2[p ^ 1])[tid] = b2v;
        }
        // single barrier per chunk:
        //  RAW: writes to buf[p^1] above vs reads of buf[p^1] at iter c+1
        //  WAR: reads of buf[p] above vs writes to buf[p] at iter c+1
        __syncthreads();
    }

    // ---- src inverse norms for this block's 128 cols (sm folded)
    if (tid < 256) ((float*)sqS)[tid] = sss;
    __syncthreads();
    if (tid < 128) {
        float ns = sqrtf(sqS[0][tid] + sqS[1][tid]);
        float smv = src_masks[bn * 256 + half * 128 + tid];
        invS[tid] = (smv != 0.f) ? 1.f / fmaxf(ns, 1e-12f) : 0.f;
    }
    __syncthreads();

    // ---- normalize + threshold + row/col argmax
    // C/D layout: col = l5, row = (reg&3) + 8*(reg>>2) + 4*h   [m74/m101]
    float isv[2]; int sgl[2];
    #pragma unroll
    for (int j = 0; j < 2; ++j) {
        isv[j] = invS[wn * 64 + j * 32 + l5];
        sgl[j] = half * 128 + wn * 64 + j * 32 + l5;   // global s index
    }
    float cbv[2]; int cbi[2];
    #pragma unroll
    for (int j = 0; j < 2; ++j) { cbv[j] = -1.f; cbi[j] = 0; }

    #pragma unroll
    for (int i = 0; i < 2; ++i) {
        #pragma unroll
        for (int r = 0; r < 16; ++r) {
            int trow = wm * 64 + i * 32 + (r & 3) + 8 * (r >> 2) + 4 * h;
            float it = invT[trow];   // broadcast
            float v[2];
            #pragma unroll
            for (int j = 0; j < 2; ++j) {
                float x = acc[i][j][r] * it * isv[j];
                v[j] = (x >= 0.05f) ? x : 0.f;
            }
            // row candidate (j ascending = s ascending; strict > keeps first)
            float bv = -1.f; int bi = 0;
            #pragma unroll
            for (int j = 0; j < 2; ++j)
                if (v[j] > bv) { bv = v[j]; bi = sgl[j]; }
            #pragma unroll
            for (int off = 1; off < 32; off <<= 1) {
                float ov = __shfl_xor(bv, off, 64);
                int   oi = __shfl_xor(bi, off, 64);
                if (ov > bv || (ov == bv && oi < bi)) { bv = ov; bi = oi; }
            }
            if (l5 == 0) { rowv[wn][trow] = bv; rowi[wn][trow] = bi; }
            // col accumulate (trow ascending within lane)
            #pragma unroll
            for (int j = 0; j < 2; ++j)
                if (v[j] > cbv[j]) { cbv[j] = v[j]; cbi[j] = trow; }
        }
    }
    #pragma unroll
    for (int j = 0; j < 2; ++j) {
        float bv = cbv[j]; int bi = cbi[j];
        float ov = __shfl_xor(bv, 32, 64);
        int   oi = __shfl_xor(bi, 32, 64);
        if (ov > bv || (ov == bv && oi < bi)) { bv = ov; bi = oi; }
        if (h == 0) { colv[wm][wn * 64 + j * 32 + l5] = bv; coli[wm][wn * 64 + j * 32 + l5] = bi; }
    }
    __syncthreads();
    if (tid < 256) {
        float v0 = rowv[0][tid]; int i0 = rowi[0][tid];
        float v1 = rowv[1][tid]; int i1 = rowi[1][tid];
        // wn0 indices always < wn1 indices -> tie keeps wn0
        if (v1 > v0 || (v1 == v0 && i1 < i0)) { v0 = v1; i0 = i1; }
        w_rowv[lbh * 256 + tid] = v0;
        w_rowi[lbh * 256 + tid] = i0;
    }
    if (tid < 128) {
        float bv = colv[0][tid]; int bi = coli[0][tid];
        #pragma unroll
        for (int q = 1; q < 4; ++q) {
            float ov = colv[q][tid]; int oi = coli[q][tid];
            if (ov > bv || (ov == bv && oi < bi)) { bv = ov; bi = oi; }
        }
        w_s2tv[bn * 256 + half * 128 + tid] = bv;
        w_s2ti[bn * 256 + half * 128 + tid] = bi;
    }
}

// ---------------- kernel 2: combine halves + cycle-consistency matching ----------------
__global__ void combine_kernel(const float* __restrict__ w_rowv, const int* __restrict__ w_rowi,
                               const float* __restrict__ w_s2tv, const int* __restrict__ w_s2ti,
                               const float* __restrict__ src_masks, const float* __restrict__ tar_mask,
                               float* __restrict__ w_score, float* __restrict__ w_mall,
                               float* __restrict__ w_savg, int* __restrict__ w_idx,
                               float* __restrict__ out) {
    int bn = blockIdx.x; int b = bn >> 5; int t = threadIdx.x;
    __shared__ float sc_s2t[256]; __shared__ int ix_s2t[256];
    __shared__ float sm[256];
    __shared__ float red[8];
    sc_s2t[t] = w_s2tv[bn * 256 + t];
    ix_s2t[t] = w_s2ti[bn * 256 + t];
    sm[t]     = src_masks[bn * 256 + t];
    float v0 = w_rowv[(bn * 2) * 256 + t];     int i0 = w_rowi[(bn * 2) * 256 + t];
    float v1 = w_rowv[(bn * 2 + 1) * 256 + t]; int i1 = w_rowi[(bn * 2 + 1) * 256 + t];
    float st2s; int i;
    if (v1 > v0 || (v1 == v0 && i1 < i0)) { st2s = v1; i = i1; }
    else                                  { st2s = v0; i = i0; }
    float tmv = tar_mask[b * 256 + t];
    __syncthreads();

    bool msim = st2s >= 0.05f;
    int is2s = ix_s2t[i];
    int dw = (is2s & 15) - (t & 15);
    int dh = (is2s >> 4) - (t >> 4);
    bool cyc = (dw * dw + dh * dh <= 4) && (sc_s2t[i] >= 0.05f);
    float mnz = tmv * sm[i] *
                ((ix_s2t[t] != 0) ? 1.f : 0.f) *
                ((i != 0) ? 1.f : 0.f);
    float mall = (msim && cyc) ? mnz : 0.f;
    w_score[bn * 256 + t] = st2s;
    w_mall[bn * 256 + t]  = mall;
    w_idx[bn * 256 + t]   = i;

    float cnt = mall, svs = st2s * mall;
    #pragma unroll
    for (int off = 1; off < 64; off <<= 1) {
        cnt += __shfl_xor(cnt, off, 64);
        svs += __shfl_xor(svs, off, 64);
    }
    if ((t & 63) == 0) {
        red[(t >> 6) * 2]     = cnt;
        red[(t >> 6) * 2 + 1] = svs;
    }
    __syncthreads();
    if (t == 0) {
        float c = red[0] + red[2] + red[4] + red[6];
        float s = red[1] + red[3] + red[5] + red[7];
        w_savg[bn] = (c > 0.f) ? (s * (1.f / 256.f)) : 0.f;
        out[51280 + bn] = c;   // match_counts
    }
}

// ---------------- kernel 3: top-k + formatting ----------------
__global__ void final_kernel(const float* __restrict__ w_score,
                             const float* __restrict__ w_mall,
                             const float* __restrict__ w_savg,
                             const int*   __restrict__ w_idx,
                             float* __restrict__ out) {
    int b = blockIdx.x, tid = threadIdx.x;
    __shared__ float savg[32];
    __shared__ int   topid[5];
    __shared__ float topv[5];
    if (tid < 32) savg[tid] = w_savg[b * 32 + tid];
    __syncthreads();
    if (tid == 0) {
        unsigned used = 0;
        for (int k = 0; k < 5; ++k) {
            float bv = -1e30f; int bi = 0;
            for (int n = 0; n < 32; ++n) {
                if (!((used >> n) & 1u) && savg[n] > bv) { bv = savg[n]; bi = n; }
            }
            used |= (1u << bi);
            topid[k] = bi; topv[k] = bv;
        }
    }
    __syncthreads();
    if (tid < 5) {
        out[b * 5 + tid]      = (float)topid[tid];   // id_src
        out[40 + b * 5 + tid] = topv[tid];           // score_src
    }
    int t = tid;
    for (int k = 0; k < 5; ++k) {
        int bn = b * 32 + topid[k];
        float sc = w_score[bn * 256 + t];
        float ma = w_mall[bn * 256 + t];
        int   ii = w_idx[bn * 256 + t];
        int o = (b * 5 + k) * 256 + t;
        out[80 + o] = sc;                            // score_pts
        bool nz = (ma != 0.f);
        out[10320 + 2 * o]     = nz ? (float)(t & 15)  : -1.f;  // tar_pts w
        out[10320 + 2 * o + 1] = nz ? (float)(t >> 4)  : -1.f;  // tar_pts h
        out[30800 + 2 * o]     = nz ? (float)(ii & 15) : -1.f;  // src_pts w
        out[30800 + 2 * o + 1] = nz ? (float)(ii >> 4) : -1.f;  // src_pts h
    }
}

extern "C" void kernel_launch(void* const* d_in, const int* in_sizes, int n_in,
                              void* d_out, int out_size, void* d_ws, size_t ws_size,
                              hipStream_t stream) {
    const float* src_feats = (const float*)d_in[0];
    const float* tar_feat  = (const float*)d_in[1];
    const float* src_masks = (const float*)d_in[2];
    const float* tar_mask  = (const float*)d_in[3];
    float* out = (float*)d_out;

    // workspace layout (~12 MB)
    const size_t PLANE = (size_t)N_B * NCH * 512 * 8;   // u16 elements per plane
    u16* tS0 = (u16*)d_ws;
    u16* tS1 = tS0 + PLANE;
    u16* tS2 = tS1 + PLANE;
    float* partT  = (float*)(tS2 + PLANE);              // 8*48*256
    float* w_invT = partT + (size_t)N_B * NCH * 256;    // 2048
    float* w_rowv = w_invT + 2048;                      // 512*256
    int*   w_rowi = (int*)(w_rowv + 512 * 256);         // 512*256
    float* w_s2tv = (float*)(w_rowi + 512 * 256);       // 256*256
    int*   w_s2ti = (int*)(w_s2tv + 256 * 256);         // 256*256
    float* w_score = (float*)(w_s2ti + 256 * 256);      // 256*256
    float* w_mall  = w_score + 256 * 256;               // 256*256
    float* w_savg  = w_mall + 256 * 256;                // 256
    int*   w_idx   = (int*)(w_savg + 256);              // 256*256

    tar_split_kernel<<<N_B * NCH, 512, 0, stream>>>(tar_feat, tS0, tS1, tS2, partT);
    invt_kernel<<<N_B, 256, 0, stream>>>(partT, tar_mask, w_invT);
    sim_kernel<<<N_B * N_N * 2, 512, 0, stream>>>(src_feats, tS0, tS1, tS2, w_invT,
                                                  src_masks,
                                                  w_rowv, w_rowi, w_s2tv, w_s2ti);
    combine_kernel<<<N_B * N_N, 256, 0, stream>>>(w_rowv, w_rowi, w_s2tv, w_s2ti,
                                                  src_masks, tar_mask,
                                                  w_score, w_mall, w_savg, w_idx, out);
    final_kernel<<<N_B, 256, 0, stream>>>(w_score, w_mall, w_savg, w_idx, out);
}

// Round 2
// 372.616 us; speedup vs baseline: 1.0516x; 1.0516x over previous
//
#include <hip/hip_runtime.h>

#define T_PATCH 256
#define C_DIM   768
#define NCH     48      // C_DIM / 16
#define N_B     8
#define N_N     32

typedef unsigned short u16;
typedef u16   u16x8  __attribute__((ext_vector_type(8)));
typedef u16   u16x4  __attribute__((ext_vector_type(4)));
typedef short s16x8  __attribute__((ext_vector_type(8)));
typedef float f32x16 __attribute__((ext_vector_type(16)));

__device__ __forceinline__ unsigned rne16(unsigned u) {
    // fp32 bits -> bf16 bits, round-to-nearest-even
    return (u + 0x7fffu + ((u >> 16) & 1u)) >> 16;
}

// 3-way RNE bf16 split: x ~= h0 + h1 + h2, |h1|<=2^-8|x|, |h2|<=2^-16|x|
__device__ __forceinline__ void split3(float x, u16& o0, u16& o1, u16& o2) {
    unsigned u0 = rne16(__float_as_uint(x));
    float f0 = __uint_as_float(u0 << 16);
    float r1 = x - f0;
    unsigned u1 = rne16(__float_as_uint(r1));
    float f1 = __uint_as_float(u1 << 16);
    float r2 = r1 - f1;
    o0 = (u16)u0; o1 = (u16)u1; o2 = (u16)(__float_as_uint(r2) >> 16);
}

// direct global->LDS copy, 16 B per lane (dest must be linear in lane order)
__device__ __forceinline__ void gll16(const u16* g, u16* l) {
    __builtin_amdgcn_global_load_lds(
        (const __attribute__((address_space(1))) unsigned int*)g,
        (__attribute__((address_space(3))) unsigned int*)l, 16, 0, 0);
}

// ---------------- kernel 0a: pre-split tar into 3 bf16 planes (MFMA-fragment layout) ----
// plane layout: [b][chunk][g][t][8]  (slot index = (b*48+c)*512 + g*256 + t)
// This layout is BOTH the LDS image (linear in tid -> global_load_lds works)
// and the A-fragment layout.
__global__ void tar_split_kernel(const float* __restrict__ tar,
                                 u16* __restrict__ tS0, u16* __restrict__ tS1,
                                 u16* __restrict__ tS2, float* __restrict__ partT) {
    int blk = blockIdx.x;            // b*48 + c
    int b = blk / NCH, c = blk - b * NCH;
    int tid = threadIdx.x;           // 0..511
    int g = tid >> 8, t = tid & 255;
    const float* tb = tar + (size_t)b * C_DIM * T_PATCH;
    float ss = 0.f;
    u16x8 v0, v1, v2;
    #pragma unroll
    for (int j = 0; j < 8; ++j) {
        float x = tb[(c * 16 + g * 8 + j) * T_PATCH + t];
        u16 a, bb, cc;
        split3(x, a, bb, cc);
        v0[j] = a; v1[j] = bb; v2[j] = cc;
        ss = fmaf(x, x, ss);
    }
    size_t off = ((size_t)blk * 512 + tid) * 8;
    *(u16x8*)(tS0 + off) = v0;
    *(u16x8*)(tS1 + off) = v1;
    *(u16x8*)(tS2 + off) = v2;
    __shared__ float sq[512];
    sq[tid] = ss;
    __syncthreads();
    if (tid < 256) partT[blk * 256 + tid] = sq[tid] + sq[tid + 256];
}

// ---------------- kernel 0b: tar inverse norms (tm folded) ----------------
__global__ void invt_kernel(const float* __restrict__ partT,
                            const float* __restrict__ tar_mask,
                            float* __restrict__ w_invT) {
    int b = blockIdx.x, t = threadIdx.x;
    float s = 0.f;
    for (int c = 0; c < NCH; ++c) s += partT[(b * NCH + c) * 256 + t];
    float tm = tar_mask[b * 256 + t];
    w_invT[b * 256 + t] = (tm != 0.f) ? 1.f / fmaxf(sqrtf(s), 1e-12f) : 0.f;
}

// ---------------- kernel 1: per-(b,n,half) GEMM + partial argmax ----------------
// Round-7: single-barrier pipeline with ONE-CHUNK prefetch depth on BOTH operands.
//  - A planes: global_load_lds (16B/lane) into double-buffered LDS, issued for
//    chunk c+1 at the top of iteration c -> full MFMA phase hides L2 latency.
//    (Round-6 lesson: A-frags loaded globally and consumed immediately by MFMA
//     expose ~200-900cy per chunk; prefetch depth 0 was the regression.)
//  - B: reg-staged (split3 needs regs), double-buffered, write-late (T14);
//    yv loads issued BEFORE the gll ops so a counted vmcnt can wait on yv
//    while the 3 gll stay in flight.
//  - B split3 spread over all 512 threads (4 elems each).
//  - ONE __syncthreads per chunk (its vmcnt0/lgkm0 drain is the only wait).
//  - Epilogue LDS overlaid on A region (dead after final barrier) -> 72 KB,
//    2 blocks/CU preserved.
__launch_bounds__(512, 4)
__global__ void sim_kernel(const float* __restrict__ src_feats,
                           const u16* __restrict__ tS0, const u16* __restrict__ tS1,
                           const u16* __restrict__ tS2,
                           const float* __restrict__ w_invT,
                           const float* __restrict__ src_masks,
                           float* __restrict__ w_rowv, int* __restrict__ w_rowi,
                           float* __restrict__ w_s2tv, int* __restrict__ w_s2ti) {
    // 72 KB flat LDS, carved:
    //  Af0/Af1/Af2: 8192 u16 each  = [p][g*256+t][8]   (16 KB/plane, dbuf)
    //  Bf0/Bf1/Bf2: 4096 u16 each  = [p][g*128+col][8] ( 8 KB/plane, dbuf)
    __shared__ __align__(16) u16 SM[36864];
    u16* Af0 = SM;
    u16* Af1 = SM + 8192;
    u16* Af2 = SM + 16384;
    u16* Bf0 = SM + 24576;
    u16* Bf1 = SM + 28672;
    u16* Bf2 = SM + 32768;
    // epilogue overlay on A region (valid only after the loop's final barrier)
    float* sqv  = (float*)(SM);           // [512]
    float* rowv = (float*)(SM + 1024);    // [2][256]
    int*   rowi = (int*)  (SM + 3072);    // [2][256]
    float* colv = (float*)(SM + 5120);    // [4][128]
    int*   coli = (int*)  (SM + 6144);    // [4][128]
    float* invT = (float*)(SM + 7168);    // [256]
    float* invS = (float*)(SM + 7680);    // [128]

    int bh = blockIdx.x;
    // XCD swizzle: b == XCD id -> each XCD's L2 holds exactly one b's tar planes
    int b    = bh & 7;
    int loc  = bh >> 3;
    int n    = loc >> 1;
    int half = loc & 1;
    int bn   = b * N_N + n;
    int lbh  = bn * 2 + half;   // logical (b,n,half) index for outputs

    int tid = threadIdx.x;
    int lane = tid & 63, w = tid >> 6;     // 8 waves
    int wm = w >> 1, wn = w & 1;           // 4 m-groups x 2 n-groups (64x64 tile)
    int h = lane >> 5, l5 = lane & 31;
    // B staging role: 512 threads, 4 elems each
    int colB = tid & 127, qB = tid >> 7;   // qB 0..3
    int gq = qB >> 1, quad = qB & 1;       // k-group (0/1), k-quad (0/1)

    // B source: this thread's first element (row gq*8+quad*4, col half*128+colB)
    const float* psrc = src_feats + (size_t)bn * C_DIM * T_PATCH
                      + (size_t)(gq * 8 + quad * 4) * T_PATCH + half * 128 + colB;
    // A plane source: chunk base advances 4096 u16/chunk; per-lane 16 B at tid*8
    size_t abase = (size_t)b * NCH * 4096 + (size_t)tid * 8;
    const u16* pga0 = tS0 + abase;
    const u16* pga1 = tS1 + abase;
    const u16* pga2 = tS2 + abase;

    f32x16 acc[2][2];
    #pragma unroll
    for (int i = 0; i < 2; ++i)
        #pragma unroll
        for (int j = 0; j < 2; ++j) acc[i][j] = (f32x16)0.0f;

    float sss = 0.f;

    // ---- prologue: stage chunk 0 (A via gll into buf0, B via split3 into buf0)
    {
        float yv[4];
        #pragma unroll
        for (int j = 0; j < 4; ++j) yv[j] = psrc[j * T_PATCH];
        psrc += 4096;
        gll16(pga0, Af0 + tid * 8);
        gll16(pga1, Af1 + tid * 8);
        gll16(pga2, Af2 + tid * 8);
        pga0 += 4096; pga1 += 4096; pga2 += 4096;
        u16x4 b0v, b1v, b2v;
        #pragma unroll
        for (int j = 0; j < 4; ++j) {
            u16 a, bb, cc;
            split3(yv[j], a, bb, cc);
            b0v[j] = a; b1v[j] = bb; b2v[j] = cc;
            sss = fmaf(yv[j], yv[j], sss);
        }
        int bslot = (gq * 128 + colB) * 8 + quad * 4;
        *(u16x4*)(Bf0 + bslot) = b0v;
        *(u16x4*)(Bf1 + bslot) = b1v;
        *(u16x4*)(Bf2 + bslot) = b2v;
    }
    __syncthreads();

    for (int c = 0; c < NCH; ++c) {
        int p = c & 1;
        bool pf = (c < NCH - 1);

        // issue-early: next chunk's B source values (4 loads; issued FIRST so
        // the split3 wait is a counted vmcnt leaving the glls in flight)
        float yv[4];
        if (pf) {
            #pragma unroll
            for (int j = 0; j < 4; ++j) yv[j] = psrc[j * T_PATCH];
            psrc += 4096;
        }
        // prefetch next A chunk into buf p^1 (safe: p^1 reads finished at the
        // barrier ending iteration c-1)
        if (pf) {
            int adst = (p ^ 1) * 4096 + tid * 8;
            gll16(pga0, Af0 + adst);
            gll16(pga1, Af1 + adst);
            gll16(pga2, Af2 + adst);
            pga0 += 4096; pga1 += 4096; pga2 += 4096;
        }

        // ---- MFMA cluster on buffers p (LDS-only operands: lgkm waits only)
        __builtin_amdgcn_s_setprio(1);
        s16x8 a0[2], a1[2], a2[2];
        {
            const u16* Ab = Af0 + p * 4096 + (h * 256 + wm * 64 + l5) * 8;
            #pragma unroll
            for (int i = 0; i < 2; ++i) a0[i] = *(const s16x8*)(Ab + i * 256);
            Ab = Af1 + p * 4096 + (h * 256 + wm * 64 + l5) * 8;
            #pragma unroll
            for (int i = 0; i < 2; ++i) a1[i] = *(const s16x8*)(Ab + i * 256);
            Ab = Af2 + p * 4096 + (h * 256 + wm * 64 + l5) * 8;
            #pragma unroll
            for (int i = 0; i < 2; ++i) a2[i] = *(const s16x8*)(Ab + i * 256);
        }
        #pragma unroll
        for (int j = 0; j < 2; ++j) {
            int boff = p * 2048 + (h * 128 + wn * 64 + j * 32 + l5) * 8;
            s16x8 b0 = *(const s16x8*)(Bf0 + boff);
            s16x8 b1 = *(const s16x8*)(Bf1 + boff);
            s16x8 b2 = *(const s16x8*)(Bf2 + boff);
            #pragma unroll
            for (int i = 0; i < 2; ++i) {
                acc[i][j] = __builtin_amdgcn_mfma_f32_32x32x16_bf16(a0[i], b0, acc[i][j], 0, 0, 0);
                acc[i][j] = __builtin_amdgcn_mfma_f32_32x32x16_bf16(a0[i], b1, acc[i][j], 0, 0, 0);
                acc[i][j] = __builtin_amdgcn_mfma_f32_32x32x16_bf16(a1[i], b0, acc[i][j], 0, 0, 0);
                acc[i][j] = __builtin_amdgcn_mfma_f32_32x32x16_bf16(a1[i], b1, acc[i][j], 0, 0, 0);
                acc[i][j] = __builtin_amdgcn_mfma_f32_32x32x16_bf16(a0[i], b2, acc[i][j], 0, 0, 0);
                acc[i][j] = __builtin_amdgcn_mfma_f32_32x32x16_bf16(a2[i], b0, acc[i][j], 0, 0, 0);
            }
        }
        __builtin_amdgcn_s_setprio(0);

        // ---- write-late: split3 next B chunk into buf p^1
        if (pf) {
            u16x4 b0v, b1v, b2v;
            #pragma unroll
            for (int j = 0; j < 4; ++j) {
                u16 a, bb, cc;
                split3(yv[j], a, bb, cc);
                b0v[j] = a; b1v[j] = bb; b2v[j] = cc;
                sss = fmaf(yv[j], yv[j], sss);
            }
            int bslot = (p ^ 1) * 2048 + (gq * 128 + colB) * 8 + quad * 4;
            *(u16x4*)(Bf0 + bslot) = b0v;
            *(u16x4*)(Bf1 + bslot) = b1v;
            *(u16x4*)(Bf2 + bslot) = b2v;
        }
        // ONE barrier per chunk (vmcnt0 drain: glls have had the whole
        // MFMA+split3 phase to land).
        //  RAW: B/A writes to buf p^1 vs reads at iter c+1
        //  WAR: reads of buf p vs writes at iter c+1
        __syncthreads();
    }

    // ---- epilogue (overlay region now safe: final loop barrier passed)
    sqv[tid] = sss;
    if (tid < 256) invT[tid] = w_invT[b * 256 + tid];
    __syncthreads();
    if (tid < 128) {
        float ns = sqrtf(sqv[tid] + sqv[tid + 128] + sqv[tid + 256] + sqv[tid + 384]);
        float smv = src_masks[bn * 256 + half * 128 + tid];
        invS[tid] = (smv != 0.f) ? 1.f / fmaxf(ns, 1e-12f) : 0.f;
    }
    __syncthreads();

    // ---- normalize + threshold + row/col argmax
    // C/D layout: col = l5, row = (reg&3) + 8*(reg>>2) + 4*h   [m74/m101]
    float isv[2]; int sgl[2];
    #pragma unroll
    for (int j = 0; j < 2; ++j) {
        isv[j] = invS[wn * 64 + j * 32 + l5];
        sgl[j] = half * 128 + wn * 64 + j * 32 + l5;   // global s index
    }
    float cbv[2]; int cbi[2];
    #pragma unroll
    for (int j = 0; j < 2; ++j) { cbv[j] = -1.f; cbi[j] = 0; }

    #pragma unroll
    for (int i = 0; i < 2; ++i) {
        #pragma unroll
        for (int r = 0; r < 16; ++r) {
            int trow = wm * 64 + i * 32 + (r & 3) + 8 * (r >> 2) + 4 * h;
            float it = invT[trow];   // broadcast
            float v[2];
            #pragma unroll
            for (int j = 0; j < 2; ++j) {
                float x = acc[i][j][r] * it * isv[j];
                v[j] = (x >= 0.05f) ? x : 0.f;
            }
            // row candidate (j ascending = s ascending; strict > keeps first)
            float bv = -1.f; int bi = 0;
            #pragma unroll
            for (int j = 0; j < 2; ++j)
                if (v[j] > bv) { bv = v[j]; bi = sgl[j]; }
            #pragma unroll
            for (int off = 1; off < 32; off <<= 1) {
                float ov = __shfl_xor(bv, off, 64);
                int   oi = __shfl_xor(bi, off, 64);
                if (ov > bv || (ov == bv && oi < bi)) { bv = ov; bi = oi; }
            }
            if (l5 == 0) { rowv[wn * 256 + trow] = bv; rowi[wn * 256 + trow] = bi; }
            // col accumulate (trow ascending within lane)
            #pragma unroll
            for (int j = 0; j < 2; ++j)
                if (v[j] > cbv[j]) { cbv[j] = v[j]; cbi[j] = trow; }
        }
    }
    #pragma unroll
    for (int j = 0; j < 2; ++j) {
        float bv = cbv[j]; int bi = cbi[j];
        float ov = __shfl_xor(bv, 32, 64);
        int   oi = __shfl_xor(bi, 32, 64);
        if (ov > bv || (ov == bv && oi < bi)) { bv = ov; bi = oi; }
        if (h == 0) { colv[wm * 128 + wn * 64 + j * 32 + l5] = bv;
                      coli[wm * 128 + wn * 64 + j * 32 + l5] = bi; }
    }
    __syncthreads();
    if (tid < 256) {
        float v0 = rowv[tid];       int i0 = rowi[tid];
        float v1 = rowv[256 + tid]; int i1 = rowi[256 + tid];
        // wn0 indices always < wn1 indices -> tie keeps wn0
        if (v1 > v0 || (v1 == v0 && i1 < i0)) { v0 = v1; i0 = i1; }
        w_rowv[lbh * 256 + tid] = v0;
        w_rowi[lbh * 256 + tid] = i0;
    }
    if (tid < 128) {
        float bv = colv[tid]; int bi = coli[tid];
        #pragma unroll
        for (int q = 1; q < 4; ++q) {
            float ov = colv[q * 128 + tid]; int oi = coli[q * 128 + tid];
            if (ov > bv || (ov == bv && oi < bi)) { bv = ov; bi = oi; }
        }
        w_s2tv[bn * 256 + half * 128 + tid] = bv;
        w_s2ti[bn * 256 + half * 128 + tid] = bi;
    }
}

// ---------------- kernel 2: combine halves + cycle-consistency matching ----------------
__global__ void combine_kernel(const float* __restrict__ w_rowv, const int* __restrict__ w_rowi,
                               const float* __restrict__ w_s2tv, const int* __restrict__ w_s2ti,
                               const float* __restrict__ src_masks, const float* __restrict__ tar_mask,
                               float* __restrict__ w_score, float* __restrict__ w_mall,
                               float* __restrict__ w_savg, int* __restrict__ w_idx,
                               float* __restrict__ out) {
    int bn = blockIdx.x; int b = bn >> 5; int t = threadIdx.x;
    __shared__ float sc_s2t[256]; __shared__ int ix_s2t[256];
    __shared__ float sm[256];
    __shared__ float red[8];
    sc_s2t[t] = w_s2tv[bn * 256 + t];
    ix_s2t[t] = w_s2ti[bn * 256 + t];
    sm[t]     = src_masks[bn * 256 + t];
    float v0 = w_rowv[(bn * 2) * 256 + t];     int i0 = w_rowi[(bn * 2) * 256 + t];
    float v1 = w_rowv[(bn * 2 + 1) * 256 + t]; int i1 = w_rowi[(bn * 2 + 1) * 256 + t];
    float st2s; int i;
    if (v1 > v0 || (v1 == v0 && i1 < i0)) { st2s = v1; i = i1; }
    else                                  { st2s = v0; i = i0; }
    float tmv = tar_mask[b * 256 + t];
    __syncthreads();

    bool msim = st2s >= 0.05f;
    int is2s = ix_s2t[i];
    int dw = (is2s & 15) - (t & 15);
    int dh = (is2s >> 4) - (t >> 4);
    bool cyc = (dw * dw + dh * dh <= 4) && (sc_s2t[i] >= 0.05f);
    float mnz = tmv * sm[i] *
                ((ix_s2t[t] != 0) ? 1.f : 0.f) *
                ((i != 0) ? 1.f : 0.f);
    float mall = (msim && cyc) ? mnz : 0.f;
    w_score[bn * 256 + t] = st2s;
    w_mall[bn * 256 + t]  = mall;
    w_idx[bn * 256 + t]   = i;

    float cnt = mall, svs = st2s * mall;
    #pragma unroll
    for (int off = 1; off < 64; off <<= 1) {
        cnt += __shfl_xor(cnt, off, 64);
        svs += __shfl_xor(svs, off, 64);
    }
    if ((t & 63) == 0) {
        red[(t >> 6) * 2]     = cnt;
        red[(t >> 6) * 2 + 1] = svs;
    }
    __syncthreads();
    if (t == 0) {
        float c = red[0] + red[2] + red[4] + red[6];
        float s = red[1] + red[3] + red[5] + red[7];
        w_savg[bn] = (c > 0.f) ? (s * (1.f / 256.f)) : 0.f;
        out[51280 + bn] = c;   // match_counts
    }
}

// ---------------- kernel 3: top-k + formatting ----------------
__global__ void final_kernel(const float* __restrict__ w_score,
                             const float* __restrict__ w_mall,
                             const float* __restrict__ w_savg,
                             const int*   __restrict__ w_idx,
                             float* __restrict__ out) {
    int b = blockIdx.x, tid = threadIdx.x;
    __shared__ float savg[32];
    __shared__ int   topid[5];
    __shared__ float topv[5];
    if (tid < 32) savg[tid] = w_savg[b * 32 + tid];
    __syncthreads();
    if (tid == 0) {
        unsigned used = 0;
        for (int k = 0; k < 5; ++k) {
            float bv = -1e30f; int bi = 0;
            for (int n = 0; n < 32; ++n) {
                if (!((used >> n) & 1u) && savg[n] > bv) { bv = savg[n]; bi = n; }
            }
            used |= (1u << bi);
            topid[k] = bi; topv[k] = bv;
        }
    }
    __syncthreads();
    if (tid < 5) {
        out[b * 5 + tid]      = (float)topid[tid];   // id_src
        out[40 + b * 5 + tid] = topv[tid];           // score_src
    }
    int t = tid;
    for (int k = 0; k < 5; ++k) {
        int bn = b * 32 + topid[k];
        float sc = w_score[bn * 256 + t];
        float ma = w_mall[bn * 256 + t];
        int   ii = w_idx[bn * 256 + t];
        int o = (b * 5 + k) * 256 + t;
        out[80 + o] = sc;                            // score_pts
        bool nz = (ma != 0.f);
        out[10320 + 2 * o]     = nz ? (float)(t & 15)  : -1.f;  // tar_pts w
        out[10320 + 2 * o + 1] = nz ? (float)(t >> 4)  : -1.f;  // tar_pts h
        out[30800 + 2 * o]     = nz ? (float)(ii & 15) : -1.f;  // src_pts w
        out[30800 + 2 * o + 1] = nz ? (float)(ii >> 4) : -1.f;  // src_pts h
    }
}

extern "C" void kernel_launch(void* const* d_in, const int* in_sizes, int n_in,
                              void* d_out, int out_size, void* d_ws, size_t ws_size,
                              hipStream_t stream) {
    const float* src_feats = (const float*)d_in[0];
    const float* tar_feat  = (const float*)d_in[1];
    const float* src_masks = (const float*)d_in[2];
    const float* tar_mask  = (const float*)d_in[3];
    float* out = (float*)d_out;

    // workspace layout (~12 MB)
    const size_t PLANE = (size_t)N_B * NCH * 512 * 8;   // u16 elements per plane
    u16* tS0 = (u16*)d_ws;
    u16* tS1 = tS0 + PLANE;
    u16* tS2 = tS1 + PLANE;
    float* partT  = (float*)(tS2 + PLANE);              // 8*48*256
    float* w_invT = partT + (size_t)N_B * NCH * 256;    // 2048
    float* w_rowv = w_invT + 2048;                      // 512*256
    int*   w_rowi = (int*)(w_rowv + 512 * 256);         // 512*256
    float* w_s2tv = (float*)(w_rowi + 512 * 256);       // 256*256
    int*   w_s2ti = (int*)(w_s2tv + 256 * 256);         // 256*256
    float* w_score = (float*)(w_s2ti + 256 * 256);      // 256*256
    float* w_mall  = w_score + 256 * 256;               // 256*256
    float* w_savg  = w_mall + 256 * 256;                // 256
    int*   w_idx   = (int*)(w_savg + 256);              // 256*256

    tar_split_kernel<<<N_B * NCH, 512, 0, stream>>>(tar_feat, tS0, tS1, tS2, partT);
    invt_kernel<<<N_B, 256, 0, stream>>>(partT, tar_mask, w_invT);
    sim_kernel<<<N_B * N_N * 2, 512, 0, stream>>>(src_feats, tS0, tS1, tS2, w_invT,
                                                  src_masks,
                                                  w_rowv, w_rowi, w_s2tv, w_s2ti);
    combine_kernel<<<N_B * N_N, 256, 0, stream>>>(w_rowv, w_rowi, w_s2tv, w_s2ti,
                                                  src_masks, tar_mask,
                                                  w_score, w_mall, w_savg, w_idx, out);
    final_kernel<<<N_B, 256, 0, stream>>>(w_score, w_mall, w_savg, w_idx, out);
}